// Round 4
// baseline (402.489 us; speedup 1.0000x reference)
//
#include <hip/hip_runtime.h>

// ScaleDotProduct (BERT attention) B=4 H=16 S=2048 D=64 fp32 in/out.
// bf16 MFMA flash attention, key-split waves, fixed-max softmax (m=12),
// S^T = K*Q^T so P^T (C-layout) is directly the PV B-fragment (padded j>=4).
// Round 4: Q-frags hoisted to regs, dead V loads dropped, mask in regs,
// double-buffered K/V staging (1 barrier/iter), register-only prep transpose.
// MFMA 16x16x32 layouts (verified m89/m91): A[m=lane&15][k=quad*8+j],
// B[k=quad*8+j][n=lane&15], C/D: col=lane&15, row=quad*4+reg.

typedef __attribute__((ext_vector_type(8))) short short8;
typedef __attribute__((ext_vector_type(4))) float floatx4;

#define S_LEN 2048
#define D_DIM 64
#define NT    32
#define L2E   1.44269504089f
#define MFIX  12.0f

static __device__ __forceinline__ unsigned short f2b(float x) {  // RNE
  union { float f; unsigned int u; } c; c.f = x;
  return (unsigned short)((c.u + 0x7FFFu + ((c.u >> 16) & 1u)) >> 16);
}
static __device__ __forceinline__ unsigned int rhu(float x) {    // round-half-up bf16 bits
  union { float f; unsigned int u; } c; c.f = x;
  return (c.u + 0x8000u) >> 16;
}
static __device__ __forceinline__ void load_lds16(const void* g, void* l) {
  __builtin_amdgcn_global_load_lds(
      (const __attribute__((address_space(1))) unsigned int*)g,
      (__attribute__((address_space(3))) unsigned int*)l, 16, 0, 0);
}

__global__ __launch_bounds__(256) void prep_kernel(
    const float* __restrict__ kin, const float* __restrict__ vin,
    unsigned short* __restrict__ kb, unsigned short* __restrict__ vt) {
  const int tid = threadIdx.x, bx = blockIdx.x;
  if (bx < 8192) {
    // K: fp32 -> bf16, coalesced
    const int i = (bx * 256 + tid) * 4;
    const float4 f = *(const float4*)(kin + i);
    uint2 p;
    p.x = (unsigned)f2b(f.x) | ((unsigned)f2b(f.y) << 16);
    p.y = (unsigned)f2b(f.z) | ((unsigned)f2b(f.w) << 16);
    *(uint2*)(kb + i) = p;
  } else {
    // V transpose in registers: 128-key x 64-d tile per block.
    // Reads: 16B per lane, 2KB stride (L1/L2 absorb: 32KB tile working set).
    // Writes: 16 consecutive lanes -> 256B contiguous.
    const int b2 = bx - 8192;            // 0..1023
    const int bh = b2 >> 4;
    const int k0 = (b2 & 15) * 128;
    const int kg = tid & 15;             // 8 keys each
    const int dg = tid >> 4;             // 4 d each
    const float* vp = vin + ((size_t)bh * S_LEN + k0 + kg * 8) * D_DIM + dg * 4;
    float4 f[8];
#pragma unroll
    for (int j = 0; j < 8; ++j) f[j] = *(const float4*)(vp + j * D_DIM);
    const float* ff = (const float*)&f[0];
#pragma unroll
    for (int i = 0; i < 4; ++i) {
      uint4 o;
      o.x = (unsigned)f2b(ff[0 * 4 + i]) | ((unsigned)f2b(ff[1 * 4 + i]) << 16);
      o.y = (unsigned)f2b(ff[2 * 4 + i]) | ((unsigned)f2b(ff[3 * 4 + i]) << 16);
      o.z = (unsigned)f2b(ff[4 * 4 + i]) | ((unsigned)f2b(ff[5 * 4 + i]) << 16);
      o.w = (unsigned)f2b(ff[6 * 4 + i]) | ((unsigned)f2b(ff[7 * 4 + i]) << 16);
      *(uint4*)(vt + ((size_t)bh * D_DIM + dg * 4 + i) * S_LEN + k0 + kg * 8) = o;
    }
  }
}

union SMem {
  struct {
    unsigned short K[2][64 * 64];  // double-buffered K tile (swizzled chunks)
    unsigned short V[2][64 * 64];  // double-buffered V^T tile
  } m;                             // 32 KB; Qs overlays K[1] pre-loop
  float Os[64][68];                // epilogue accumulator [q][d], padded
};

__global__ __launch_bounds__(256, 4) void flash_kernel(
    const float* __restrict__ qin, const unsigned short* __restrict__ kb,
    const unsigned short* __restrict__ vt, const float* __restrict__ mask,
    float* __restrict__ out) {
  __shared__ SMem sm;
  __shared__ float Ls[4][64];

  const int tid = threadIdx.x;
  const int w = tid >> 6, lane = tid & 63, quad = lane >> 4, lm = lane & 15;
  const int bx = blockIdx.x, bh = blockIdx.y, b = bh >> 4;
  const int q0 = bx * 64;
  const int l7 = lm & 7;

  // ---- stage Q (bf16, *0.125 folded, swizzled) into Qs = sm.m.K[1] ----
  unsigned short* Qs = sm.m.K[1];
  {
    const int row = tid >> 2, r7 = row & 7;
    const float* qp = qin + ((size_t)(bh * S_LEN + q0 + row)) * D_DIM + (tid & 3) * 16;
#pragma unroll
    for (int h = 0; h < 2; ++h) {
      const int chunk = (tid & 3) * 2 + h;
      float4 a = *(const float4*)(qp + h * 8);
      float4 c = *(const float4*)(qp + h * 8 + 4);
      uint4 o;
      o.x = (unsigned)f2b(a.x * 0.125f) | ((unsigned)f2b(a.y * 0.125f) << 16);
      o.y = (unsigned)f2b(a.z * 0.125f) | ((unsigned)f2b(a.w * 0.125f) << 16);
      o.z = (unsigned)f2b(c.x * 0.125f) | ((unsigned)f2b(c.y * 0.125f) << 16);
      o.w = (unsigned)f2b(c.z * 0.125f) | ((unsigned)f2b(c.w * 0.125f) << 16);
      *(uint4*)&Qs[row * 64 + ((chunk ^ r7) * 8)] = o;
    }
  }

  // ---- per-lane staging sources (swizzled on the global side) ----
  const int rl = lane >> 3, cl = lane & 7;
  const int swz = (cl ^ rl) * 8;
  const unsigned short* kp0 = kb + (size_t)bh * S_LEN * D_DIM + (w * 16 + rl) * 64 + swz;
  const unsigned short* kp1 = kp0 + 8 * 64;
  const unsigned short* vp0 = vt + (size_t)bh * D_DIM * S_LEN + (w * 16 + rl) * S_LEN + swz;
  const unsigned short* vp1 = vp0 + 8 * S_LEN;

  // issue tile-0 staging into buf0 (disjoint from Qs = K[1])
  load_lds16(kp0, &sm.m.K[0][(w * 16) * 64]);
  load_lds16(kp1, &sm.m.K[0][(w * 16 + 8) * 64]);
  load_lds16(vp0, &sm.m.V[0][(w * 16) * 64]);
  load_lds16(vp1, &sm.m.V[0][(w * 16 + 8) * 64]);

  // mask -> regs (quad-broadcast); fixed-max fold: (mask - 12) * log2e
  const float* mrow = mask + b * S_LEN + w * 16 + quad * 4;
  floatx4 mc;
  {
    const floatx4 ml = *(const floatx4*)mrow;
#pragma unroll
    for (int r = 0; r < 4; ++r) mc[r] = fmaf(ml[r], L2E, -MFIX * L2E);
  }

  __syncthreads();  // Q writes + buf0 staging visible

  // ---- hoist Q B-frags to registers (loop-invariant) ----
  short8 bq[4][2];
#pragma unroll
  for (int qs = 0; qs < 4; ++qs) {
    bq[qs][0] = *(const short8*)&Qs[(qs * 16 + lm) * 64 + ((quad ^ l7) * 8)];
    bq[qs][1] = *(const short8*)&Qs[(qs * 16 + lm) * 64 + (((4 + quad) ^ l7) * 8)];
  }
  __syncthreads();  // all waves done reading Qs before t=0 stages into buf1

  const int kidx0 = (w * 16 + lm) * 64 + ((quad ^ l7) * 8);
  const int kidx1 = (w * 16 + lm) * 64 + (((4 + quad) ^ l7) * 8);
  const int vc0 = (((2 * w + (quad >> 1)) & 7) ^ l7) * 8 + 4 * (quad & 1);

  floatx4 o[4][4];  // [dt][qs]
#pragma unroll
  for (int dt = 0; dt < 4; ++dt)
#pragma unroll
    for (int qs = 0; qs < 4; ++qs) o[dt][qs] = (floatx4){0.f, 0.f, 0.f, 0.f};
  float lsum[4] = {0.f, 0.f, 0.f, 0.f};

  for (int t = 0; t < NT; ++t) {
    if (t > 0) __syncthreads();  // publishes buf[t&1]; protects buf[(t+1)&1]
    const int buf = t & 1, nbuf = buf ^ 1;
    if (t + 1 < NT) {            // prefetch next tile (drained at next barrier)
      const size_t off = (size_t)(t + 1) * 4096;
      load_lds16(kp0 + off, &sm.m.K[nbuf][(w * 16) * 64]);
      load_lds16(kp1 + off, &sm.m.K[nbuf][(w * 16 + 8) * 64]);
      load_lds16(vp0 + (t + 1) * 64, &sm.m.V[nbuf][(w * 16) * 64]);
      load_lds16(vp1 + (t + 1) * 64, &sm.m.V[nbuf][(w * 16 + 8) * 64]);
    }
    floatx4 mnext;
    {
      const int tn = (t + 1 < NT) ? (t + 1) : 0;
      mnext = *(const floatx4*)(mrow + tn * 64);
    }

    const unsigned short* Kb = sm.m.K[buf];
    const unsigned short* Vb = sm.m.V[buf];
    const short8 ak0 = *(const short8*)&Kb[kidx0];
    const short8 ak1 = *(const short8*)&Kb[kidx1];

    // S^T strips + fixed-max softmax + pack P^T B-frags
    short8 bp[4];
#pragma unroll
    for (int qs = 0; qs < 4; ++qs) {
      floatx4 st = (floatx4){0.f, 0.f, 0.f, 0.f};
      st = __builtin_amdgcn_mfma_f32_16x16x32_bf16(ak0, bq[qs][0], st, 0, 0, 0);
      st = __builtin_amdgcn_mfma_f32_16x16x32_bf16(ak1, bq[qs][1], st, 0, 0, 0);
      float p[4];
#pragma unroll
      for (int r = 0; r < 4; ++r) {
        p[r] = __builtin_amdgcn_exp2f(fmaf(st[r], L2E, mc[r]));
        lsum[qs] += p[r];
      }
      union { unsigned int u[4]; short8 s; } pb;
      pb.u[0] = rhu(p[0]) | (rhu(p[1]) << 16);
      pb.u[1] = rhu(p[2]) | (rhu(p[3]) << 16);
      pb.u[2] = 0; pb.u[3] = 0;
      bp[qs] = pb.s;
    }

    // O^T += V^T * P^T  (A j=0..3 = keys quad*4..+3; j>=4 dead: B is zero there)
#pragma unroll
    for (int dt = 0; dt < 4; ++dt) {
      union { uint2 u2[2]; short8 s; } av;
      av.u2[0] = *(const uint2*)&Vb[(dt * 16 + lm) * 64 + vc0];
      av.u2[1] = av.u2[0];  // finite filler for dead j>=4 lanes-slice
#pragma unroll
      for (int qs = 0; qs < 4; ++qs)
        o[dt][qs] = __builtin_amdgcn_mfma_f32_16x16x32_bf16(av.s, bp[qs], o[dt][qs], 0, 0, 0);
    }

#pragma unroll
    for (int r = 0; r < 4; ++r) mc[r] = fmaf(mnext[r], L2E, -MFIX * L2E);
  }

  // ---- l: reduce over quads (keys), publish per-wave partials ----
#pragma unroll
  for (int qs = 0; qs < 4; ++qs) {
    float v = lsum[qs];
    v += __shfl_xor(v, 16, 64);
    v += __shfl_xor(v, 32, 64);
    lsum[qs] = v;
  }
  if (quad == 0) {
#pragma unroll
    for (int qs = 0; qs < 4; ++qs) Ls[w][qs * 16 + lm] = lsum[qs];
  }

  // ---- O^T cross-wave reduction through Os[q][d] (aliases K/V buffers) ----
#pragma unroll
  for (int ph = 0; ph < 4; ++ph) {
    __syncthreads();
    if (w == ph) {
#pragma unroll
      for (int dt = 0; dt < 4; ++dt)
#pragma unroll
        for (int qs = 0; qs < 4; ++qs) {
          float* dst = &sm.Os[qs * 16 + lm][dt * 16 + quad * 4];
          if (ph == 0) {
            *(floatx4*)dst = o[dt][qs];
          } else {
            floatx4 cur = *(const floatx4*)dst;
            *(floatx4*)dst = cur + o[dt][qs];
          }
        }
    }
  }
  __syncthreads();

  // ---- epilogue: /l, coalesced fp32 store ----
  {
    const int q = tid >> 2, dc = (tid & 3) * 16;
    const float l = Ls[0][q] + Ls[1][q] + Ls[2][q] + Ls[3][q];
    const float inv = 1.0f / l;
    float* outp = out + ((size_t)(bh * S_LEN + q0 + q)) * D_DIM + dc;
#pragma unroll
    for (int i = 0; i < 4; ++i) {
      floatx4 v = *(const floatx4*)&sm.Os[q][dc + i * 4];
      v *= inv;
      *(floatx4*)(outp + i * 4) = v;
    }
  }
}

extern "C" void kernel_launch(void* const* d_in, const int* in_sizes, int n_in,
                              void* d_out, int out_size, void* d_ws, size_t ws_size,
                              hipStream_t stream) {
  const float* q = (const float*)d_in[0];
  const float* k = (const float*)d_in[1];
  const float* v = (const float*)d_in[2];
  const float* mask = (const float*)d_in[3];
  float* out = (float*)d_out;

  unsigned short* kb = (unsigned short*)d_ws;                       // 16.78 MB
  unsigned short* vt = kb + (size_t)64 * S_LEN * D_DIM;             // 16.78 MB

  prep_kernel<<<8192 + 1024, 256, 0, stream>>>(k, v, kb, vt);
  flash_kernel<<<dim3(32, 64), 256, 0, stream>>>(q, kb, vt, mask, out);
}

// Round 5
// 268.484 us; speedup vs baseline: 1.4991x; 1.4991x over previous
//
#include <hip/hip_runtime.h>

// ScaleDotProduct (BERT attention) B=4 H=16 S=2048 D=64 fp32 in/out.
// bf16 MFMA flash attention, key-split waves, fixed-max softmax (m=12),
// S^T = K*Q^T so P^T (C-layout) is directly the PV B-fragment (padded j>=4).
// Round 5: fix round-4 spill regression. launch_bounds(256,4) capped the
// unified VGPR+AGPR file at 128/thread; hoisted Q-frags pushed demand to
// ~158 -> per-iteration scratch spills (+230MB HBM fetch). (256,3) gives a
// 170-reg budget: no spill, 3 blocks/CU, dbuf prefetch covers latency.
// MFMA 16x16x32 layouts (verified m89/m91): A[m=lane&15][k=quad*8+j],
// B[k=quad*8+j][n=lane&15], C/D: col=lane&15, row=quad*4+reg.

typedef __attribute__((ext_vector_type(8))) short short8;
typedef __attribute__((ext_vector_type(4))) float floatx4;

#define S_LEN 2048
#define D_DIM 64
#define NT    32
#define L2E   1.44269504089f
#define MFIX  12.0f

static __device__ __forceinline__ unsigned short f2b(float x) {  // RNE
  union { float f; unsigned int u; } c; c.f = x;
  return (unsigned short)((c.u + 0x7FFFu + ((c.u >> 16) & 1u)) >> 16);
}
static __device__ __forceinline__ unsigned int rhu(float x) {    // round-half-up bf16 bits
  union { float f; unsigned int u; } c; c.f = x;
  return (c.u + 0x8000u) >> 16;
}
static __device__ __forceinline__ void load_lds16(const void* g, void* l) {
  __builtin_amdgcn_global_load_lds(
      (const __attribute__((address_space(1))) unsigned int*)g,
      (__attribute__((address_space(3))) unsigned int*)l, 16, 0, 0);
}

__global__ __launch_bounds__(256) void prep_kernel(
    const float* __restrict__ kin, const float* __restrict__ vin,
    unsigned short* __restrict__ kb, unsigned short* __restrict__ vt) {
  const int tid = threadIdx.x, bx = blockIdx.x;
  if (bx < 8192) {
    // K: fp32 -> bf16, coalesced
    const int i = (bx * 256 + tid) * 4;
    const float4 f = *(const float4*)(kin + i);
    uint2 p;
    p.x = (unsigned)f2b(f.x) | ((unsigned)f2b(f.y) << 16);
    p.y = (unsigned)f2b(f.z) | ((unsigned)f2b(f.w) << 16);
    *(uint2*)(kb + i) = p;
  } else {
    // V transpose in registers: 128-key x 64-d tile per block.
    // Reads: 4-lane clusters cover 64B lines contiguously; writes 256B runs.
    const int b2 = bx - 8192;            // 0..1023
    const int bh = b2 >> 4;
    const int k0 = (b2 & 15) * 128;
    const int kg = tid & 15;             // 8 keys each
    const int dg = tid >> 4;             // 4 d each
    const float* vp = vin + ((size_t)bh * S_LEN + k0 + kg * 8) * D_DIM + dg * 4;
    float4 f[8];
#pragma unroll
    for (int j = 0; j < 8; ++j) f[j] = *(const float4*)(vp + j * D_DIM);
    const float* ff = (const float*)&f[0];
#pragma unroll
    for (int i = 0; i < 4; ++i) {
      uint4 o;
      o.x = (unsigned)f2b(ff[0 * 4 + i]) | ((unsigned)f2b(ff[1 * 4 + i]) << 16);
      o.y = (unsigned)f2b(ff[2 * 4 + i]) | ((unsigned)f2b(ff[3 * 4 + i]) << 16);
      o.z = (unsigned)f2b(ff[4 * 4 + i]) | ((unsigned)f2b(ff[5 * 4 + i]) << 16);
      o.w = (unsigned)f2b(ff[6 * 4 + i]) | ((unsigned)f2b(ff[7 * 4 + i]) << 16);
      *(uint4*)(vt + ((size_t)bh * D_DIM + dg * 4 + i) * S_LEN + k0 + kg * 8) = o;
    }
  }
}

union SMem {
  struct {
    unsigned short K[2][64 * 64];  // double-buffered K tile (swizzled chunks)
    unsigned short V[2][64 * 64];  // double-buffered V^T tile
  } m;                             // 32 KB; Qs overlays K[1] pre-loop
  float Os[64][68];                // epilogue accumulator [q][d], padded
};

__global__ __launch_bounds__(256, 3) void flash_kernel(
    const float* __restrict__ qin, const unsigned short* __restrict__ kb,
    const unsigned short* __restrict__ vt, const float* __restrict__ mask,
    float* __restrict__ out) {
  __shared__ SMem sm;
  __shared__ float Ls[4][64];

  const int tid = threadIdx.x;
  const int w = tid >> 6, lane = tid & 63, quad = lane >> 4, lm = lane & 15;
  const int bx = blockIdx.x, bh = blockIdx.y, b = bh >> 4;
  const int q0 = bx * 64;
  const int l7 = lm & 7;

  // ---- stage Q (bf16, *0.125 folded, swizzled) into Qs = sm.m.K[1] ----
  unsigned short* Qs = sm.m.K[1];
  {
    const int row = tid >> 2, r7 = row & 7;
    const float* qp = qin + ((size_t)(bh * S_LEN + q0 + row)) * D_DIM + (tid & 3) * 16;
#pragma unroll
    for (int h = 0; h < 2; ++h) {
      const int chunk = (tid & 3) * 2 + h;
      float4 a = *(const float4*)(qp + h * 8);
      float4 c = *(const float4*)(qp + h * 8 + 4);
      uint4 o;
      o.x = (unsigned)f2b(a.x * 0.125f) | ((unsigned)f2b(a.y * 0.125f) << 16);
      o.y = (unsigned)f2b(a.z * 0.125f) | ((unsigned)f2b(a.w * 0.125f) << 16);
      o.z = (unsigned)f2b(c.x * 0.125f) | ((unsigned)f2b(c.y * 0.125f) << 16);
      o.w = (unsigned)f2b(c.z * 0.125f) | ((unsigned)f2b(c.w * 0.125f) << 16);
      *(uint4*)&Qs[row * 64 + ((chunk ^ r7) * 8)] = o;
    }
  }

  // ---- per-lane staging sources (swizzled on the global side) ----
  const int rl = lane >> 3, cl = lane & 7;
  const int swz = (cl ^ rl) * 8;
  const unsigned short* kp0 = kb + (size_t)bh * S_LEN * D_DIM + (w * 16 + rl) * 64 + swz;
  const unsigned short* kp1 = kp0 + 8 * 64;
  const unsigned short* vp0 = vt + (size_t)bh * D_DIM * S_LEN + (w * 16 + rl) * S_LEN + swz;
  const unsigned short* vp1 = vp0 + 8 * S_LEN;

  // issue tile-0 staging into buf0 (disjoint from Qs = K[1])
  load_lds16(kp0, &sm.m.K[0][(w * 16) * 64]);
  load_lds16(kp1, &sm.m.K[0][(w * 16 + 8) * 64]);
  load_lds16(vp0, &sm.m.V[0][(w * 16) * 64]);
  load_lds16(vp1, &sm.m.V[0][(w * 16 + 8) * 64]);

  // mask -> regs (quad-broadcast); fixed-max fold: (mask - 12) * log2e
  const float* mrow = mask + b * S_LEN + w * 16 + quad * 4;
  floatx4 mc;
  {
    const floatx4 ml = *(const floatx4*)mrow;
#pragma unroll
    for (int r = 0; r < 4; ++r) mc[r] = fmaf(ml[r], L2E, -MFIX * L2E);
  }

  __syncthreads();  // Q writes + buf0 staging visible

  // ---- hoist Q B-frags to registers (loop-invariant) ----
  short8 bq[4][2];
#pragma unroll
  for (int qs = 0; qs < 4; ++qs) {
    bq[qs][0] = *(const short8*)&Qs[(qs * 16 + lm) * 64 + ((quad ^ l7) * 8)];
    bq[qs][1] = *(const short8*)&Qs[(qs * 16 + lm) * 64 + (((4 + quad) ^ l7) * 8)];
  }
  __syncthreads();  // all waves done reading Qs before t=0 stages into buf1

  const int kidx0 = (w * 16 + lm) * 64 + ((quad ^ l7) * 8);
  const int kidx1 = (w * 16 + lm) * 64 + (((4 + quad) ^ l7) * 8);
  const int vc0 = (((2 * w + (quad >> 1)) & 7) ^ l7) * 8 + 4 * (quad & 1);

  floatx4 o[4][4];  // [dt][qs]
#pragma unroll
  for (int dt = 0; dt < 4; ++dt)
#pragma unroll
    for (int qs = 0; qs < 4; ++qs) o[dt][qs] = (floatx4){0.f, 0.f, 0.f, 0.f};
  float lsum[4] = {0.f, 0.f, 0.f, 0.f};

  for (int t = 0; t < NT; ++t) {
    if (t > 0) __syncthreads();  // publishes buf[t&1]; protects buf[(t+1)&1]
    const int buf = t & 1, nbuf = buf ^ 1;
    if (t + 1 < NT) {            // prefetch next tile (drained at next barrier)
      const size_t off = (size_t)(t + 1) * 4096;
      load_lds16(kp0 + off, &sm.m.K[nbuf][(w * 16) * 64]);
      load_lds16(kp1 + off, &sm.m.K[nbuf][(w * 16 + 8) * 64]);
      load_lds16(vp0 + (t + 1) * 64, &sm.m.V[nbuf][(w * 16) * 64]);
      load_lds16(vp1 + (t + 1) * 64, &sm.m.V[nbuf][(w * 16 + 8) * 64]);
    }
    floatx4 mnext;
    {
      const int tn = (t + 1 < NT) ? (t + 1) : 0;
      mnext = *(const floatx4*)(mrow + tn * 64);
    }

    const unsigned short* Kb = sm.m.K[buf];
    const unsigned short* Vb = sm.m.V[buf];
    const short8 ak0 = *(const short8*)&Kb[kidx0];
    const short8 ak1 = *(const short8*)&Kb[kidx1];

    // S^T strips + fixed-max softmax + pack P^T B-frags
    short8 bp[4];
#pragma unroll
    for (int qs = 0; qs < 4; ++qs) {
      floatx4 st = (floatx4){0.f, 0.f, 0.f, 0.f};
      st = __builtin_amdgcn_mfma_f32_16x16x32_bf16(ak0, bq[qs][0], st, 0, 0, 0);
      st = __builtin_amdgcn_mfma_f32_16x16x32_bf16(ak1, bq[qs][1], st, 0, 0, 0);
      float p[4];
#pragma unroll
      for (int r = 0; r < 4; ++r) {
        p[r] = __builtin_amdgcn_exp2f(fmaf(st[r], L2E, mc[r]));
        lsum[qs] += p[r];
      }
      union { unsigned int u[4]; short8 s; } pb;
      pb.u[0] = rhu(p[0]) | (rhu(p[1]) << 16);
      pb.u[1] = rhu(p[2]) | (rhu(p[3]) << 16);
      pb.u[2] = 0; pb.u[3] = 0;
      bp[qs] = pb.s;
    }

    // O^T += V^T * P^T  (A j=0..3 = keys quad*4..+3; j>=4 dead: B is zero there)
#pragma unroll
    for (int dt = 0; dt < 4; ++dt) {
      union { uint2 u2[2]; short8 s; } av;
      av.u2[0] = *(const uint2*)&Vb[(dt * 16 + lm) * 64 + vc0];
      av.u2[1] = av.u2[0];  // finite filler for dead j>=4 lanes-slice
#pragma unroll
      for (int qs = 0; qs < 4; ++qs)
        o[dt][qs] = __builtin_amdgcn_mfma_f32_16x16x32_bf16(av.s, bp[qs], o[dt][qs], 0, 0, 0);
    }

#pragma unroll
    for (int r = 0; r < 4; ++r) mc[r] = fmaf(mnext[r], L2E, -MFIX * L2E);
  }

  // ---- l: reduce over quads (keys), publish per-wave partials ----
#pragma unroll
  for (int qs = 0; qs < 4; ++qs) {
    float v = lsum[qs];
    v += __shfl_xor(v, 16, 64);
    v += __shfl_xor(v, 32, 64);
    lsum[qs] = v;
  }
  if (quad == 0) {
#pragma unroll
    for (int qs = 0; qs < 4; ++qs) Ls[w][qs * 16 + lm] = lsum[qs];
  }

  // ---- O^T cross-wave reduction through Os[q][d] (aliases K/V buffers) ----
#pragma unroll
  for (int ph = 0; ph < 4; ++ph) {
    __syncthreads();
    if (w == ph) {
#pragma unroll
      for (int dt = 0; dt < 4; ++dt)
#pragma unroll
        for (int qs = 0; qs < 4; ++qs) {
          float* dst = &sm.Os[qs * 16 + lm][dt * 16 + quad * 4];
          if (ph == 0) {
            *(floatx4*)dst = o[dt][qs];
          } else {
            floatx4 cur = *(const floatx4*)dst;
            *(floatx4*)dst = cur + o[dt][qs];
          }
        }
    }
  }
  __syncthreads();

  // ---- epilogue: /l, coalesced fp32 store ----
  {
    const int q = tid >> 2, dc = (tid & 3) * 16;
    const float l = Ls[0][q] + Ls[1][q] + Ls[2][q] + Ls[3][q];
    const float inv = 1.0f / l;
    float* outp = out + ((size_t)(bh * S_LEN + q0 + q)) * D_DIM + dc;
#pragma unroll
    for (int i = 0; i < 4; ++i) {
      floatx4 v = *(const floatx4*)&sm.Os[q][dc + i * 4];
      v *= inv;
      *(floatx4*)(outp + i * 4) = v;
    }
  }
}

extern "C" void kernel_launch(void* const* d_in, const int* in_sizes, int n_in,
                              void* d_out, int out_size, void* d_ws, size_t ws_size,
                              hipStream_t stream) {
  const float* q = (const float*)d_in[0];
  const float* k = (const float*)d_in[1];
  const float* v = (const float*)d_in[2];
  const float* mask = (const float*)d_in[3];
  float* out = (float*)d_out;

  unsigned short* kb = (unsigned short*)d_ws;                       // 16.78 MB
  unsigned short* vt = kb + (size_t)64 * S_LEN * D_DIM;             // 16.78 MB

  prep_kernel<<<8192 + 1024, 256, 0, stream>>>(k, v, kb, vt);
  flash_kernel<<<dim3(32, 64), 256, 0, stream>>>(q, kb, vt, mask, out);
}

// Round 6
// 239.333 us; speedup vs baseline: 1.6817x; 1.1218x over previous
//
#include <hip/hip_runtime.h>

// ScaleDotProduct (BERT attention) B=4 H=16 S=2048 D=64 fp32 in/out.
// bf16 MFMA flash attention, key-split waves, fixed-max softmax (m=12),
// S^T = K*Q^T so P^T (C-layout) is directly the PV B-fragment.
// Round 6: paired-tile PV — two 64-key tiles fill a FULL K=32 PV B-frag
// (j=0..3 from tile t-1, j=4..7 from tile t), halving PV MFMA count.
// V rotates through 3 LDS buffers so tile t-1 survives the t+1 prefetch.
// launch_bounds(256,3): 170-reg budget, no spill (r4 lesson: (256,4) spilled).
// MFMA 16x16x32 layouts (verified m89/m91): A[m=lane&15][k=quad*8+j],
// B[k=quad*8+j][n=lane&15], C/D: col=lane&15, row=quad*4+reg.

typedef __attribute__((ext_vector_type(8))) short short8;
typedef __attribute__((ext_vector_type(4))) float floatx4;

#define S_LEN 2048
#define D_DIM 64
#define NT    32
#define L2E   1.44269504089f
#define MFIX  12.0f

static __device__ __forceinline__ unsigned short f2b(float x) {  // RNE
  union { float f; unsigned int u; } c; c.f = x;
  return (unsigned short)((c.u + 0x7FFFu + ((c.u >> 16) & 1u)) >> 16);
}
static __device__ __forceinline__ unsigned int rhu(float x) {    // round-half-up bf16 bits
  union { float f; unsigned int u; } c; c.f = x;
  return (c.u + 0x8000u) >> 16;
}
static __device__ __forceinline__ void load_lds16(const void* g, void* l) {
  __builtin_amdgcn_global_load_lds(
      (const __attribute__((address_space(1))) unsigned int*)g,
      (__attribute__((address_space(3))) unsigned int*)l, 16, 0, 0);
}

__global__ __launch_bounds__(256) void prep_kernel(
    const float* __restrict__ kin, const float* __restrict__ vin,
    unsigned short* __restrict__ kb, unsigned short* __restrict__ vt) {
  const int tid = threadIdx.x, bx = blockIdx.x;
  if (bx < 8192) {
    // K: fp32 -> bf16, coalesced
    const int i = (bx * 256 + tid) * 4;
    const float4 f = *(const float4*)(kin + i);
    uint2 p;
    p.x = (unsigned)f2b(f.x) | ((unsigned)f2b(f.y) << 16);
    p.y = (unsigned)f2b(f.z) | ((unsigned)f2b(f.w) << 16);
    *(uint2*)(kb + i) = p;
  } else {
    // V transpose in registers: 128-key x 64-d tile per block.
    const int b2 = bx - 8192;            // 0..1023
    const int bh = b2 >> 4;
    const int k0 = (b2 & 15) * 128;
    const int kg = tid & 15;             // 8 keys each
    const int dg = tid >> 4;             // 4 d each
    const float* vp = vin + ((size_t)bh * S_LEN + k0 + kg * 8) * D_DIM + dg * 4;
    float4 f[8];
#pragma unroll
    for (int j = 0; j < 8; ++j) f[j] = *(const float4*)(vp + j * D_DIM);
    const float* ff = (const float*)&f[0];
#pragma unroll
    for (int i = 0; i < 4; ++i) {
      uint4 o;
      o.x = (unsigned)f2b(ff[0 * 4 + i]) | ((unsigned)f2b(ff[1 * 4 + i]) << 16);
      o.y = (unsigned)f2b(ff[2 * 4 + i]) | ((unsigned)f2b(ff[3 * 4 + i]) << 16);
      o.z = (unsigned)f2b(ff[4 * 4 + i]) | ((unsigned)f2b(ff[5 * 4 + i]) << 16);
      o.w = (unsigned)f2b(ff[6 * 4 + i]) | ((unsigned)f2b(ff[7 * 4 + i]) << 16);
      *(uint4*)(vt + ((size_t)bh * D_DIM + dg * 4 + i) * S_LEN + k0 + kg * 8) = o;
    }
  }
}

union SMem {
  struct {
    unsigned short K[2][64 * 64];  // double-buffered K tile (chunk-swizzled)
    unsigned short V[3][64 * 64];  // triple-buffered V^T tile (t-1 must survive)
  } m;                             // 40 KB; Qs overlays K[1] pre-loop
  float Os[64][68];                // epilogue accumulator [q][d], padded
};

__global__ __launch_bounds__(256, 3) void flash_kernel(
    const float* __restrict__ qin, const unsigned short* __restrict__ kb,
    const unsigned short* __restrict__ vt, const float* __restrict__ mask,
    float* __restrict__ out) {
  __shared__ SMem sm;
  __shared__ float Ls[4][64];

  const int tid = threadIdx.x;
  const int w = tid >> 6, lane = tid & 63, quad = lane >> 4, lm = lane & 15;
  const int bx = blockIdx.x, bh = blockIdx.y, b = bh >> 4;
  const int q0 = bx * 64;
  const int l7 = lm & 7;

  // ---- stage Q (bf16, *0.125 folded, swizzled) into Qs = sm.m.K[1] ----
  unsigned short* Qs = sm.m.K[1];
  {
    const int row = tid >> 2, r7 = row & 7;
    const float* qp = qin + ((size_t)(bh * S_LEN + q0 + row)) * D_DIM + (tid & 3) * 16;
#pragma unroll
    for (int h = 0; h < 2; ++h) {
      const int chunk = (tid & 3) * 2 + h;
      float4 a = *(const float4*)(qp + h * 8);
      float4 c = *(const float4*)(qp + h * 8 + 4);
      uint4 o;
      o.x = (unsigned)f2b(a.x * 0.125f) | ((unsigned)f2b(a.y * 0.125f) << 16);
      o.y = (unsigned)f2b(a.z * 0.125f) | ((unsigned)f2b(a.w * 0.125f) << 16);
      o.z = (unsigned)f2b(c.x * 0.125f) | ((unsigned)f2b(c.y * 0.125f) << 16);
      o.w = (unsigned)f2b(c.z * 0.125f) | ((unsigned)f2b(c.w * 0.125f) << 16);
      *(uint4*)&Qs[row * 64 + ((chunk ^ r7) * 8)] = o;
    }
  }

  // ---- per-lane staging sources (swizzled on the global side) ----
  const int rl = lane >> 3, cl = lane & 7;
  const int swz = (cl ^ rl) * 8;
  const unsigned short* kp0 = kb + (size_t)bh * S_LEN * D_DIM + (w * 16 + rl) * 64 + swz;
  const unsigned short* kp1 = kp0 + 8 * 64;
  const unsigned short* vp0 = vt + (size_t)bh * D_DIM * S_LEN + (w * 16 + rl) * S_LEN + swz;
  const unsigned short* vp1 = vp0 + 8 * S_LEN;
  const int ldsA = (w * 16) * 64, ldsB = (w * 16 + 8) * 64;

  // issue tile-0 staging into K[0] / V[0] (disjoint from Qs = K[1])
  load_lds16(kp0, &sm.m.K[0][ldsA]);
  load_lds16(kp1, &sm.m.K[0][ldsB]);
  load_lds16(vp0, &sm.m.V[0][ldsA]);
  load_lds16(vp1, &sm.m.V[0][ldsB]);

  // mask -> regs (quad-broadcast); fixed-max fold: (mask - 12) * log2e
  const float* mrow = mask + b * S_LEN + w * 16 + quad * 4;
  floatx4 mc;
  {
    const floatx4 ml = *(const floatx4*)mrow;
#pragma unroll
    for (int r = 0; r < 4; ++r) mc[r] = fmaf(ml[r], L2E, -MFIX * L2E);
  }

  __syncthreads();  // Q writes + tile-0 staging visible

  // ---- hoist Q B-frags to registers (loop-invariant) ----
  short8 bq[4][2];
#pragma unroll
  for (int qs = 0; qs < 4; ++qs) {
    bq[qs][0] = *(const short8*)&Qs[(qs * 16 + lm) * 64 + ((quad ^ l7) * 8)];
    bq[qs][1] = *(const short8*)&Qs[(qs * 16 + lm) * 64 + (((4 + quad) ^ l7) * 8)];
  }
  __syncthreads();  // all waves done reading Qs before t=0 prefetches into K[1]

  const int kidx0 = (w * 16 + lm) * 64 + ((quad ^ l7) * 8);
  const int kidx1 = (w * 16 + lm) * 64 + (((4 + quad) ^ l7) * 8);
  const int vc0 = (((2 * w + (quad >> 1)) & 7) ^ l7) * 8 + 4 * (quad & 1);

  // rotating V pointers: at iter t, vT = tile t, vTm1 = tile t-1, vTp1 = staging
  unsigned short* vTm1 = sm.m.V[2];
  unsigned short* vT   = sm.m.V[0];
  unsigned short* vTp1 = sm.m.V[1];

  floatx4 o[4][4];  // [dt][qs]
#pragma unroll
  for (int dt = 0; dt < 4; ++dt)
#pragma unroll
    for (int qs = 0; qs < 4; ++qs) o[dt][qs] = (floatx4){0.f, 0.f, 0.f, 0.f};
  float lsum[4] = {0.f, 0.f, 0.f, 0.f};
  uint4 pb[4];  // P^T B-frags, filled over an iter pair (x,y = even; z,w = odd)

#pragma unroll 2
  for (int t = 0; t < NT; ++t) {
    if (t > 0) __syncthreads();  // publishes tile t; protects prefetch targets
    const unsigned short* kcur = (t & 1) ? sm.m.K[1] : sm.m.K[0];
    unsigned short* knext = (t & 1) ? sm.m.K[0] : sm.m.K[1];
    if (t + 1 < NT) {            // prefetch next tile (drained at next barrier)
      const size_t off = (size_t)(t + 1) * 4096;
      load_lds16(kp0 + off, knext + ldsA);
      load_lds16(kp1 + off, knext + ldsB);
      load_lds16(vp0 + (t + 1) * 64, vTp1 + ldsA);
      load_lds16(vp1 + (t + 1) * 64, vTp1 + ldsB);
    }
    floatx4 mnext;
    {
      const int tn = (t + 1 < NT) ? (t + 1) : 0;
      mnext = *(const floatx4*)(mrow + tn * 64);
    }

    const short8 ak0 = *(const short8*)&kcur[kidx0];
    const short8 ak1 = *(const short8*)&kcur[kidx1];

    // S^T strips + fixed-max softmax + pack into the pair's B-frag half
#pragma unroll
    for (int qs = 0; qs < 4; ++qs) {
      floatx4 st = (floatx4){0.f, 0.f, 0.f, 0.f};
      st = __builtin_amdgcn_mfma_f32_16x16x32_bf16(ak0, bq[qs][0], st, 0, 0, 0);
      st = __builtin_amdgcn_mfma_f32_16x16x32_bf16(ak1, bq[qs][1], st, 0, 0, 0);
      float p[4];
#pragma unroll
      for (int r = 0; r < 4; ++r) {
        p[r] = __builtin_amdgcn_exp2f(fmaf(st[r], L2E, mc[r]));
        lsum[qs] += p[r];
      }
      const unsigned lo = rhu(p[0]) | (rhu(p[1]) << 16);
      const unsigned hi = rhu(p[2]) | (rhu(p[3]) << 16);
      if ((t & 1) == 0) { pb[qs].x = lo; pb[qs].y = hi; }
      else             { pb[qs].z = lo; pb[qs].w = hi; }
    }

    // paired PV at odd t: full K=32 — j=0..3 keys from tile t-1, j=4..7 from t
    if (t & 1) {
#pragma unroll
      for (int dt = 0; dt < 4; ++dt) {
        const int vrow = (dt * 16 + lm) * 64 + vc0;
        union { uint2 u2[2]; short8 s; } av;
        av.u2[0] = *(const uint2*)&vTm1[vrow];
        av.u2[1] = *(const uint2*)&vT[vrow];
#pragma unroll
        for (int qs = 0; qs < 4; ++qs) {
          union { uint4 u; short8 s; } bp;
          bp.u = pb[qs];
          o[dt][qs] = __builtin_amdgcn_mfma_f32_16x16x32_bf16(av.s, bp.s, o[dt][qs], 0, 0, 0);
        }
      }
    }

    // rotate V buffers; advance mask
    unsigned short* tmp = vTm1; vTm1 = vT; vT = vTp1; vTp1 = tmp;
#pragma unroll
    for (int r = 0; r < 4; ++r) mc[r] = fmaf(mnext[r], L2E, -MFIX * L2E);
  }

  // ---- l: reduce over quads (keys), publish per-wave partials ----
#pragma unroll
  for (int qs = 0; qs < 4; ++qs) {
    float v = lsum[qs];
    v += __shfl_xor(v, 16, 64);
    v += __shfl_xor(v, 32, 64);
    lsum[qs] = v;
  }
  if (quad == 0) {
#pragma unroll
    for (int qs = 0; qs < 4; ++qs) Ls[w][qs * 16 + lm] = lsum[qs];
  }

  // ---- O^T cross-wave reduction through Os[q][d] (aliases K/V buffers) ----
#pragma unroll
  for (int ph = 0; ph < 4; ++ph) {
    __syncthreads();
    if (w == ph) {
#pragma unroll
      for (int dt = 0; dt < 4; ++dt)
#pragma unroll
        for (int qs = 0; qs < 4; ++qs) {
          float* dst = &sm.Os[qs * 16 + lm][dt * 16 + quad * 4];
          if (ph == 0) {
            *(floatx4*)dst = o[dt][qs];
          } else {
            floatx4 cur = *(const floatx4*)dst;
            *(floatx4*)dst = cur + o[dt][qs];
          }
        }
    }
  }
  __syncthreads();

  // ---- epilogue: /l, coalesced fp32 store ----
  {
    const int q = tid >> 2, dc = (tid & 3) * 16;
    const float l = Ls[0][q] + Ls[1][q] + Ls[2][q] + Ls[3][q];
    const float inv = 1.0f / l;
    float* outp = out + ((size_t)(bh * S_LEN + q0 + q)) * D_DIM + dc;
#pragma unroll
    for (int i = 0; i < 4; ++i) {
      floatx4 v = *(const floatx4*)&sm.Os[q][dc + i * 4];
      v *= inv;
      *(floatx4*)(outp + i * 4) = v;
    }
  }
}

extern "C" void kernel_launch(void* const* d_in, const int* in_sizes, int n_in,
                              void* d_out, int out_size, void* d_ws, size_t ws_size,
                              hipStream_t stream) {
  const float* q = (const float*)d_in[0];
  const float* k = (const float*)d_in[1];
  const float* v = (const float*)d_in[2];
  const float* mask = (const float*)d_in[3];
  float* out = (float*)d_out;

  unsigned short* kb = (unsigned short*)d_ws;                       // 16.78 MB
  unsigned short* vt = kb + (size_t)64 * S_LEN * D_DIM;             // 16.78 MB

  prep_kernel<<<8192 + 1024, 256, 0, stream>>>(k, v, kb, vt);
  flash_kernel<<<dim3(32, 64), 256, 0, stream>>>(q, kb, vt, mask, out);
}